// Round 4
// baseline (605.421 us; speedup 1.0000x reference)
//
#include <hip/hip_runtime.h>

#define S_LEN 2048
#define R_LEN 384
#define C_DIM 64

typedef unsigned short u16;
typedef unsigned int u32;
typedef __attribute__((ext_vector_type(8))) short s8v;
typedef __attribute__((ext_vector_type(4))) float f4v;

__device__ __forceinline__ float bf2f(u16 h) {
    union { u32 u; float f; } c; c.u = ((u32)h) << 16; return c.f;
}
__device__ __forceinline__ u16 f2bf(float f) {
    union { float f; u32 u; } c; c.f = f;
    return (u16)((c.u + 0x7fffu + ((c.u >> 16) & 1u)) >> 16);
}
__device__ __forceinline__ void unpack8(uint4 q, float* o) {
    o[0] = bf2f((u16)(q.x & 0xffffu)); o[1] = bf2f((u16)(q.x >> 16));
    o[2] = bf2f((u16)(q.y & 0xffffu)); o[3] = bf2f((u16)(q.y >> 16));
    o[4] = bf2f((u16)(q.z & 0xffffu)); o[5] = bf2f((u16)(q.z >> 16));
    o[6] = bf2f((u16)(q.w & 0xffffu)); o[7] = bf2f((u16)(q.w >> 16));
}
// split y into bf16 hi + bf16 lo (compensated): hi+lo ~ fp32-accurate
__device__ __forceinline__ void split8(const float* y, uint4& qh, uint4& ql) {
    u16 h[8]; u16 l[8];
    #pragma unroll
    for (int j = 0; j < 8; ++j) {
        h[j] = f2bf(y[j]);
        l[j] = f2bf(y[j] - bf2f(h[j]));
    }
    qh.x = (u32)h[0] | ((u32)h[1] << 16); qh.y = (u32)h[2] | ((u32)h[3] << 16);
    qh.z = (u32)h[4] | ((u32)h[5] << 16); qh.w = (u32)h[6] | ((u32)h[7] << 16);
    ql.x = (u32)l[0] | ((u32)l[1] << 16); ql.y = (u32)l[2] | ((u32)l[3] << 16);
    ql.z = (u32)l[4] | ((u32)l[5] << 16); ql.w = (u32)l[6] | ((u32)l[7] << 16);
}
__device__ __forceinline__ void load8f(const float* p, float* o) {
    float4 a = *(const float4*)p;
    float4 b = *(const float4*)(p + 4);
    o[0] = a.x; o[1] = a.y; o[2] = a.z; o[3] = a.w;
    o[4] = b.x; o[5] = b.y; o[6] = b.z; o[7] = b.w;
}
// xs tile: [256 rows][64 bf16] = 128 B/row; XOR-swizzle 16B slots by row&7 (bank-conflict fix, G4/T2)
#define XS_SWZ(row, bc) ((((int)(row)) << 7) + (((int)(bc)) ^ ((((int)(row)) & 7) << 4)))

// ---------------- K1: per-column attention -> o1[r][64] (fp32) ----------------
__global__ __launch_bounds__(256) void k1_colattn(
    const float* __restrict__ act, const float* __restrict__ lnsp, const float* __restrict__ lnbp,
    const float* __restrict__ wq, const float* __restrict__ wk, const float* __restrict__ wv,
    float* __restrict__ o1g)
{
    __shared__ __align__(16) char smem[32768 + 32768 + 65536 + 8192 + 1024 + 512];
    char* xsh = smem;                                        // 32 KiB: LN'd x hi (bf16, swizzled)
    char* xsl = smem + 32768;                                // 32 KiB: LN'd x lo residual
    char* kvb = smem + 65536;                                // 64 KiB: kv [2048][16] bf16, swizzled
    float* scrA = (float*)(smem + 131072);                   // [256][8] reduce scratch
    float* scrC = (float*)(smem + 139264);                   // [4][64] o1 wave partials
    float* qavg = (float*)(smem + 140288);                   // [64]
    float* qlds = qavg + 64;                                 // [64]

    const int t = threadIdx.x;
    const int r = blockIdx.x;
    const int lane = t & 63;
    const int w = t >> 6;
    const int grp = t & 7;      // channel-slice group (8 lanes per row)
    const int rowb = t >> 3;    // 0..31
    const int n16 = lane & 15;
    const int kgrp = lane >> 4;

    float lns_r[8], lnb_r[8];
    load8f(lnsp + grp * 8, lns_r);
    load8f(lnbp + grp * 8, lnb_r);

    // B fragments for kv GEMM: B[k][n] = wk[k][n] (n<8) | wv[k][n-8]
    s8v bkv0, bkv1;
    {
        #pragma unroll
        for (int j = 0; j < 8; ++j) {
            int k0 = (kgrp << 3) + j;
            float e0 = (n16 < 8) ? wk[k0 * 8 + n16] : wv[k0 * 8 + (n16 - 8)];
            float e1 = (n16 < 8) ? wk[(k0 + 32) * 8 + n16] : wv[(k0 + 32) * 8 + (n16 - 8)];
            bkv0[j] = (short)f2bf(e0); bkv1[j] = (short)f2bf(e1);
        }
    }

    float qacc[8];
    #pragma unroll
    for (int j = 0; j < 8; ++j) qacc[j] = 0.f;

    for (int ci = 0; ci < 8; ++ci) {
        __syncthreads();   // previous chunk's LDS consumers done
        #pragma unroll
        for (int sub = 0; sub < 8; ++sub) {
            int row = sub * 32 + rowb;
            int s = ci * 256 + row;
            float xf[8];
            load8f(act + ((size_t)s * R_LEN + r) * C_DIM + grp * 8, xf);
            float sum = 0.f, sq = 0.f;
            #pragma unroll
            for (int j = 0; j < 8; ++j) { sum += xf[j]; sq += xf[j] * xf[j]; }
            #pragma unroll
            for (int m = 1; m <= 4; m <<= 1) { sum += __shfl_xor(sum, m); sq += __shfl_xor(sq, m); }
            float mu = sum * (1.f / 64.f);
            float var = sq * (1.f / 64.f) - mu * mu;
            float rstd = rsqrtf(var + 1e-5f);
            float yv[8];
            #pragma unroll
            for (int j = 0; j < 8; ++j) {
                yv[j] = (xf[j] - mu) * rstd * lns_r[j] + lnb_r[j];
                qacc[j] += yv[j];
            }
            uint4 qh, ql; split8(yv, qh, ql);
            *(uint4*)(xsh + XS_SWZ(row, grp * 16)) = qh;
            *(uint4*)(xsl + XS_SWZ(row, grp * 16)) = ql;
        }
        __syncthreads();
        // kv = X @ [wk|wv] via MFMA (A-side hi/lo); wave handles 4 row-tiles
        #pragma unroll
        for (int i4 = 0; i4 < 4; ++i4) {
            int tile = w * 4 + i4;
            s8v a0h = *(const s8v*)(xsh + XS_SWZ(tile * 16 + n16, kgrp * 16));
            s8v a1h = *(const s8v*)(xsh + XS_SWZ(tile * 16 + n16, 64 + kgrp * 16));
            s8v a0l = *(const s8v*)(xsl + XS_SWZ(tile * 16 + n16, kgrp * 16));
            s8v a1l = *(const s8v*)(xsl + XS_SWZ(tile * 16 + n16, 64 + kgrp * 16));
            f4v acc = {0.f, 0.f, 0.f, 0.f};
            acc = __builtin_amdgcn_mfma_f32_16x16x32_bf16(a0h, bkv0, acc, 0, 0, 0);
            acc = __builtin_amdgcn_mfma_f32_16x16x32_bf16(a1h, bkv1, acc, 0, 0, 0);
            acc = __builtin_amdgcn_mfma_f32_16x16x32_bf16(a0l, bkv0, acc, 0, 0, 0);
            acc = __builtin_amdgcn_mfma_f32_16x16x32_bf16(a1l, bkv1, acc, 0, 0, 0);
            #pragma unroll
            for (int jj = 0; jj < 4; ++jj) {
                int sg = ci * 256 + tile * 16 + kgrp * 4 + jj;
                int off = sg * 32 + ((n16 * 2) ^ (((sg >> 2) & 1) << 4));
                *(u16*)(kvb + off) = f2bf(acc[jj]);
            }
        }
    }

    // ---- q_avg reduce ----
    #pragma unroll
    for (int j = 0; j < 8; ++j) scrA[t * 8 + j] = qacc[j];
    __syncthreads();
    if (t < 64) {
        float s = 0.f;
        for (int k = 0; k < 32; ++k) s += scrA[((t >> 3) + 8 * k) * 8 + (t & 7)];
        qavg[t] = s * (1.f / (float)S_LEN);
    }
    __syncthreads();
    if (t < 64) {
        float s = 0.f;
        for (int c = 0; c < 64; ++c) s += qavg[c] * wq[c * 64 + t];
        qlds[t] = s * 0.35355339059327373f;   // * AC^-0.5
    }
    __syncthreads();
    float q_r[64];
    #pragma unroll
    for (int c = 0; c < 64; ++c) q_r[c] = qlds[c];

    // ---- pass A: per-h max ----
    float mx[8];
    #pragma unroll
    for (int h = 0; h < 8; ++h) mx[h] = -1e30f;
    for (int i = 0; i < 8; ++i) {
        int s = i * 256 + t;
        int sw = ((s >> 2) & 1) << 4;
        float kf[8]; unpack8(*(const uint4*)(kvb + s * 32 + sw), kf);
        #pragma unroll
        for (int h = 0; h < 8; ++h) {
            float lg = 0.f;
            #pragma unroll
            for (int a = 0; a < 8; ++a) lg += q_r[h * 8 + a] * kf[a];
            mx[h] = fmaxf(mx[h], lg);
        }
    }
    #pragma unroll
    for (int h = 0; h < 8; ++h) scrA[t * 8 + h] = mx[h];
    __syncthreads();
    for (int st = 128; st >= 1; st >>= 1) {
        if (t < st) {
            #pragma unroll
            for (int h = 0; h < 8; ++h)
                scrA[t * 8 + h] = fmaxf(scrA[t * 8 + h], scrA[(t + st) * 8 + h]);
        }
        __syncthreads();
    }
    float mxf[8];
    #pragma unroll
    for (int h = 0; h < 8; ++h) mxf[h] = scrA[h];
    __syncthreads();   // everyone read mxf before scrA reuse

    // ---- pass B: exp-sum + o1 accumulation ----
    float sm[8];
    float o1a[64];
    #pragma unroll
    for (int h = 0; h < 8; ++h) sm[h] = 0.f;
    #pragma unroll
    for (int e = 0; e < 64; ++e) o1a[e] = 0.f;
    for (int i = 0; i < 8; ++i) {
        int s = i * 256 + t;
        int sw = ((s >> 2) & 1) << 4;
        float kf[8]; unpack8(*(const uint4*)(kvb + s * 32 + sw), kf);
        float vf[8]; unpack8(*(const uint4*)(kvb + s * 32 + (16 ^ sw)), vf);
        #pragma unroll
        for (int h = 0; h < 8; ++h) {
            float lg = 0.f;
            #pragma unroll
            for (int a = 0; a < 8; ++a) lg += q_r[h * 8 + a] * kf[a];
            float p = __expf(lg - mxf[h]);
            sm[h] += p;
            #pragma unroll
            for (int a = 0; a < 8; ++a) o1a[h * 8 + a] += p * vf[a];
        }
    }
    #pragma unroll
    for (int h = 0; h < 8; ++h) scrA[t * 8 + h] = sm[h];
    __syncthreads();
    for (int st = 128; st >= 1; st >>= 1) {
        if (t < st) {
            #pragma unroll
            for (int h = 0; h < 8; ++h)
                scrA[t * 8 + h] += scrA[(t + st) * 8 + h];
        }
        __syncthreads();
    }
    // wave butterfly reduce of o1a (static indices only)
    #pragma unroll
    for (int m = 1; m < 64; m <<= 1) {
        #pragma unroll
        for (int e = 0; e < 64; ++e) o1a[e] += __shfl_xor(o1a[e], m);
    }
    #pragma unroll
    for (int e = 0; e < 64; ++e) if (lane == e) scrC[w * 64 + e] = o1a[e];
    __syncthreads();
    if (t < 64) {
        float v = scrC[t] + scrC[64 + t] + scrC[128 + t] + scrC[192 + t];
        float denom = scrA[t >> 3];
        o1g[r * 64 + t] = v / denom;
    }
}

// ---------------- K2: gate * o1 -> output projection ----------------
__global__ __launch_bounds__(256) void k2_gateout(
    const float* __restrict__ act, const float* __restrict__ lnsp, const float* __restrict__ lnbp,
    const float* __restrict__ wg, const float* __restrict__ bgp,
    const float* __restrict__ wo, const float* __restrict__ bop,
    const float* __restrict__ o1g, float* __restrict__ out)
{
    __shared__ __align__(16) char bufH[32768];   // hi bf16 (act -> tmp -> out), swizzled
    __shared__ __align__(16) char bufL[32768];   // lo bf16 residuals
    const int t = threadIdx.x;
    const int r = blockIdx.x;
    const int s0 = blockIdx.y * 256;
    const int lane = t & 63;
    const int w = t >> 6;
    const int grp = t & 7;
    const int rowb = t >> 3;
    const int n16 = lane & 15;
    const int kgrp = lane >> 4;

    float lns_r[8], lnb_r[8];
    load8f(lnsp + grp * 8, lns_r);
    load8f(lnbp + grp * 8, lnb_r);

    float o1c[4], bgc[4], boc[4];
    #pragma unroll
    for (int c4 = 0; c4 < 4; ++c4) {
        int col = c4 * 16 + n16;
        o1c[c4] = o1g[r * 64 + col];
        bgc[c4] = bgp[col];
        boc[c4] = bop[col];
    }
    s8v wgf[4][2], wof[4][2];
    #pragma unroll
    for (int c4 = 0; c4 < 4; ++c4) {
        #pragma unroll
        for (int kb = 0; kb < 2; ++kb) {
            #pragma unroll
            for (int j = 0; j < 8; ++j) {
                int k = kb * 32 + kgrp * 8 + j;
                wgf[c4][kb][j] = (short)f2bf(wg[k * 64 + c4 * 16 + n16]);
                wof[c4][kb][j] = (short)f2bf(wo[k * 64 + c4 * 16 + n16]);
            }
        }
    }

    // stage LN'd rows into LDS (bf16 hi + lo, swizzled)
    #pragma unroll
    for (int sub = 0; sub < 8; ++sub) {
        int row = sub * 32 + rowb;
        int s = s0 + row;
        float xf[8];
        load8f(act + ((size_t)s * R_LEN + r) * C_DIM + grp * 8, xf);
        float sum = 0.f, sq = 0.f;
        #pragma unroll
        for (int j = 0; j < 8; ++j) { sum += xf[j]; sq += xf[j] * xf[j]; }
        #pragma unroll
        for (int m = 1; m <= 4; m <<= 1) { sum += __shfl_xor(sum, m); sq += __shfl_xor(sq, m); }
        float mu = sum * (1.f / 64.f);
        float var = sq * (1.f / 64.f) - mu * mu;
        float rstd = rsqrtf(var + 1e-5f);
        float yv[8];
        #pragma unroll
        for (int j = 0; j < 8; ++j) yv[j] = (xf[j] - mu) * rstd * lns_r[j] + lnb_r[j];
        uint4 qh, ql; split8(yv, qh, ql);
        *(uint4*)(bufH + XS_SWZ(row, grp * 16)) = qh;
        *(uint4*)(bufL + XS_SWZ(row, grp * 16)) = ql;
    }
    __syncthreads();

    // GEMM1: gate = sigmoid(X@wg + bg); tmp = gate * o1 (hi/lo), wave-private rows
    #pragma unroll
    for (int i4 = 0; i4 < 4; ++i4) {
        int tile = w * 4 + i4;
        s8v a0h = *(const s8v*)(bufH + XS_SWZ(tile * 16 + n16, kgrp * 16));
        s8v a1h = *(const s8v*)(bufH + XS_SWZ(tile * 16 + n16, 64 + kgrp * 16));
        s8v a0l = *(const s8v*)(bufL + XS_SWZ(tile * 16 + n16, kgrp * 16));
        s8v a1l = *(const s8v*)(bufL + XS_SWZ(tile * 16 + n16, 64 + kgrp * 16));
        #pragma unroll
        for (int c4 = 0; c4 < 4; ++c4) {
            f4v acc = {0.f, 0.f, 0.f, 0.f};
            acc = __builtin_amdgcn_mfma_f32_16x16x32_bf16(a0h, wgf[c4][0], acc, 0, 0, 0);
            acc = __builtin_amdgcn_mfma_f32_16x16x32_bf16(a1h, wgf[c4][1], acc, 0, 0, 0);
            acc = __builtin_amdgcn_mfma_f32_16x16x32_bf16(a0l, wgf[c4][0], acc, 0, 0, 0);
            acc = __builtin_amdgcn_mfma_f32_16x16x32_bf16(a1l, wgf[c4][1], acc, 0, 0, 0);
            #pragma unroll
            for (int jj = 0; jj < 4; ++jj) {
                float gv = acc[jj] + bgc[c4];
                float sg = 1.f / (1.f + __expf(-gv));
                float tv = sg * o1c[c4];
                u16 th = f2bf(tv);
                u16 tl = f2bf(tv - bf2f(th));
                int row = tile * 16 + kgrp * 4 + jj;
                int off = XS_SWZ(row, (c4 * 16 + n16) * 2);
                *(u16*)(bufH + off) = th;
                *(u16*)(bufL + off) = tl;
            }
        }
    }

    // GEMM2: out = tmp @ wo + bo (hi/lo), staged back as hi + residual
    #pragma unroll
    for (int i4 = 0; i4 < 4; ++i4) {
        int tile = w * 4 + i4;
        s8v a0h = *(const s8v*)(bufH + XS_SWZ(tile * 16 + n16, kgrp * 16));
        s8v a1h = *(const s8v*)(bufH + XS_SWZ(tile * 16 + n16, 64 + kgrp * 16));
        s8v a0l = *(const s8v*)(bufL + XS_SWZ(tile * 16 + n16, kgrp * 16));
        s8v a1l = *(const s8v*)(bufL + XS_SWZ(tile * 16 + n16, 64 + kgrp * 16));
        #pragma unroll
        for (int c4 = 0; c4 < 4; ++c4) {
            f4v acc = {0.f, 0.f, 0.f, 0.f};
            acc = __builtin_amdgcn_mfma_f32_16x16x32_bf16(a0h, wof[c4][0], acc, 0, 0, 0);
            acc = __builtin_amdgcn_mfma_f32_16x16x32_bf16(a1h, wof[c4][1], acc, 0, 0, 0);
            acc = __builtin_amdgcn_mfma_f32_16x16x32_bf16(a0l, wof[c4][0], acc, 0, 0, 0);
            acc = __builtin_amdgcn_mfma_f32_16x16x32_bf16(a1l, wof[c4][1], acc, 0, 0, 0);
            #pragma unroll
            for (int jj = 0; jj < 4; ++jj) {
                float ov = acc[jj] + boc[c4];
                u16 oh = f2bf(ov);
                u16 ol = f2bf(ov - bf2f(oh));
                int row = tile * 16 + kgrp * 4 + jj;
                int off = XS_SWZ(row, (c4 * 16 + n16) * 2);
                *(u16*)(bufH + off) = oh;
                *(u16*)(bufL + off) = ol;
            }
        }
    }
    __syncthreads();

    // coalesced writeback: 32 B per lane (fp32 = hi + lo)
    #pragma unroll
    for (int sub = 0; sub < 8; ++sub) {
        int row = sub * 32 + rowb;
        int s = s0 + row;
        float yh[8], yl[8];
        unpack8(*(const uint4*)(bufH + XS_SWZ(row, grp * 16)), yh);
        unpack8(*(const uint4*)(bufL + XS_SWZ(row, grp * 16)), yl);
        float* op = out + ((size_t)s * R_LEN + r) * C_DIM + grp * 8;
        *(float4*)op = make_float4(yh[0] + yl[0], yh[1] + yl[1], yh[2] + yl[2], yh[3] + yl[3]);
        *(float4*)(op + 4) = make_float4(yh[4] + yl[4], yh[5] + yl[5], yh[6] + yl[6], yh[7] + yl[7]);
    }
}

extern "C" void kernel_launch(void* const* d_in, const int* in_sizes, int n_in,
                              void* d_out, int out_size, void* d_ws, size_t ws_size,
                              hipStream_t stream) {
    const float* act = (const float*)d_in[0];
    // d_in[1] = msa_mask: unused by the math
    const float* lns = (const float*)d_in[2];
    const float* lnb = (const float*)d_in[3];
    const float* wq  = (const float*)d_in[4];
    const float* wk  = (const float*)d_in[5];
    const float* wv  = (const float*)d_in[6];
    const float* wg  = (const float*)d_in[7];
    const float* bg  = (const float*)d_in[8];
    const float* wo  = (const float*)d_in[9];
    const float* bo  = (const float*)d_in[10];
    float* out = (float*)d_out;
    float* o1g = (float*)d_ws;   // 384*64*4 = 98304 B

    hipLaunchKernelGGL(k1_colattn, dim3(R_LEN), dim3(256), 0, stream,
                       act, lns, lnb, wq, wk, wv, o1g);
    hipLaunchKernelGGL(k2_gateout, dim3(R_LEN, 8), dim3(256), 0, stream,
                       act, lns, lnb, wg, bg, wo, bo, o1g, out);
}